// Round 5
// baseline (395.892 us; speedup 1.0000x reference)
//
#include <hip/hip_runtime.h>
#include <cstdint>
#include <cstddef>

// Problem constants
#define L_   256
#define Q_   21
#define M_   8192
#define QQ   441
#define JCH  16            // j-blocks staged per barrier in k_main
#define SCALE    32.0f     // J scaled by 32 before fp16 quantization
#define INVSCALE 0.03125f
#define NPAIR ((L_ * (L_ - 1)) / 2)   // 32640 valid (i,j) pairs

// Jt block layout (per (i,j), TRI-PACKED): pair index = i(i-1)/2 + j.
// 21 rows (k = symbol), each row 48 B = 21 fp16(J*32) + 3 pad halves.
// Row stride 12 dwords; block padded to 1024 B (256 dwords).
// Jt = NPAIR KiB ~= 32 MiB + guard (i=255 rem-stage overread of 1 block).
//
// ws layout (no memset needed -- every slot is plain-stored exactly once):
//   [0      .. 32640)   acc2[8160]  : per-prep-block J2 partials (f32)
//   [32768  .. 65536)   accL[8192]  : per-main-block ll partials (f32)
//   [65536  .. 65544)   scal[2]     : wsum, h2_sum
//   [131072 .. +2MiB)   seqsP: dword[jq*M + b] = symbols j=4jq..4jq+3 (bytes)
//   [131072+2MiB ..)    Jt (fp16 blocks, tri-packed, + guard)

#define NPREPT 8160        // transpose blocks (32 x 255), 8 pairs each
#define GPREP  (NPREPT + 256 + 2)   // + seqs-pack blocks + wsum + h2

typedef _Float16 h2 __attribute__((ext_vector_type(2)));
typedef unsigned u32x4 __attribute__((ext_vector_type(4)));   // nontemporal-ok

__device__ __forceinline__ float block_reduce_sum(float v) {
    __shared__ float s[256];
    int t = threadIdx.x;
    __syncthreads();           // guard against reuse hazard
    s[t] = v;
    __syncthreads();
#pragma unroll
    for (int o = 128; o > 0; o >>= 1) {
        if (t < o) s[t] += s[t + o];
        __syncthreads();
    }
    return s[0];
}

// ---- D1: fused prep, wave-private transpose.
// blocks [0,8160): 8 pairs/block, 2 pairs/wave, wave-private LDS (no cross-
// wave sharing). 14.3 KiB LDS -> 8 blocks/CU (32 waves) for latency hiding.
// blocks [8160,8416): seqs pack; 8416: wsum; 8417: h^2.
__global__ __launch_bounds__(256) void k_prep(const float* __restrict__ J,
                                              const int* __restrict__ seqs,
                                              const float* __restrict__ w,
                                              const float* __restrict__ h,
                                              unsigned* __restrict__ Jt,
                                              unsigned* __restrict__ seqsP,
                                              float* __restrict__ acc2,
                                              float* __restrict__ scal) {
    const int bid = blockIdx.x;
    const int t = threadIdx.x;

    if (bid < NPREPT) {
        __shared__ __align__(16) float sB[4 * 2 * 448];   // 14336 B
        const int i  = (bid >> 5) + 1;                // 1..255
        const int j0 = (bid & 31) << 3;               // 8-pair chunk
        if (j0 >= i) {                                // uniform across block
            if (t == 0) acc2[bid] = 0.f;              // slot must be defined
            return;
        }
        const int jn = min(8, i - j0);
        const int wv = t >> 6;                        // wave 0..3
        const int l  = t & 63;
        const int p0 = wv << 1;                       // pair offset 0/2/4/6
        const int pn = min(2, jn - p0);               // may be <= 0
        float* sW = sB + wv * (2 * 448);              // wave-private region

        // phase 1: load pair(s) -> wave-private LDS, accumulate sum(J^2)
        float v2 = 0.f;
        for (int pp = 0; pp < pn; ++pp) {
            const float* src = J + (size_t)(i * L_ + j0 + p0 + pp) * QQ;
            float* d = sW + pp * 448;
#pragma unroll
            for (int r = 0; r < 7; ++r) {
                const int idx = (r << 6) + l;
                if (idx < QQ) {
                    float v = __builtin_nontemporal_load(src + idx);
                    d[idx] = v;
                    v2 += v * v;
                }
            }
        }
        __syncthreads();   // belt-and-braces (wave-private data; uniform)

        // phase 2: transpose-pack; one uint4 nontemporal store per lane/pair
        const int tri = i * (i - 1) / 2;
        for (int pp = 0; pp < pn; ++pp) {
            const float* s = sW + pp * 448;
            u32x4* dst = reinterpret_cast<u32x4*>(
                Jt + (size_t)(tri + j0 + p0 + pp) * 256);
            unsigned wvv[4];
#pragma unroll
            for (int c = 0; c < 4; ++c) {
                const int dd = (l << 2) | c;          // 0..255
                const int kr = dd / 12;
                const int dw = dd - 12 * kr;
                const int a0 = dw << 1;
                unsigned outw = 0;
                if (kr < Q_) {
                    float x0 = (a0     < Q_) ? s[(a0    ) * Q_ + kr] : 0.f;
                    float x1 = (a0 + 1 < Q_) ? s[(a0 + 1) * Q_ + kr] : 0.f;
                    union { _Float16 hh[2]; unsigned u; } uu;
                    uu.hh[0] = (_Float16)(x0 * SCALE);
                    uu.hh[1] = (_Float16)(x1 * SCALE);
                    outw = uu.u;
                }
                wvv[c] = outw;
            }
            u32x4 o;
            o.x = wvv[0]; o.y = wvv[1]; o.z = wvv[2]; o.w = wvv[3];
            __builtin_nontemporal_store(o, dst + l);
        }

        float r = block_reduce_sum(v2);
        if (t == 0) acc2[bid] = r;                    // private slot, no atomic
    } else if (bid < NPREPT + 256) {
        const int u  = bid - NPREPT;
        const int b  = ((u >> 3) << 8) + t;           // b-chunk u>>3, thread b
        const int jc = u & 7;                         // jq-chunk
        const int4* row = reinterpret_cast<const int4*>(seqs + (size_t)b * L_);
#pragma unroll
        for (int u8 = 0; u8 < 8; ++u8) {
            const int jq = jc * 8 + u8;
            int4 v = row[jq];
            unsigned p = (unsigned)(v.x & 255) | ((unsigned)(v.y & 255) << 8) |
                         ((unsigned)(v.z & 255) << 16) | ((unsigned)(v.w & 255) << 24);
            seqsP[jq * M_ + b] = p;
        }
    } else if (bid == NPREPT + 256) {
        float v = 0.f;
        for (int x = t; x < M_; x += 256) v += w[x];
        float r = block_reduce_sum(v);
        if (t == 0) scal[0] = r;
    } else {
        float v2 = 0.f;
        for (int x = t; x < L_ * Q_; x += 256) { float y = h[x]; v2 += y * y; }
        float r2 = block_reduce_sum(v2);
        if (t == 0) scal[1] = r2;
    }
}

// Inner body: row k of staged block jj, 12 packed fp16 adds (24 halves incl pad).
#define BODY(jj)                                                                    \
    {                                                                               \
        const unsigned kk = (idxw[(jj) >> 2] >> (((jj) & 3) * 8)) & 255u;           \
        const uint4* rp = reinterpret_cast<const uint4*>(sJ) + ((jj) * 64 + kk * 3);\
        union { uint4 u; h2 h[4]; } ra, rb, rc;                                     \
        ra.u = rp[0]; rb.u = rp[1]; rc.u = rp[2];                                   \
        acch[0]  += ra.h[0]; acch[1]  += ra.h[1];                                   \
        acch[2]  += ra.h[2]; acch[3]  += ra.h[3];                                   \
        acch[4]  += rb.h[0]; acch[5]  += rb.h[1];                                   \
        acch[6]  += rb.h[2]; acch[7]  += rb.h[3];                                   \
        acch[8]  += rc.h[0]; acch[9]  += rc.h[1];                                   \
        acch[10] += rc.h[2]; acch[11] += rc.h[3];                                   \
    }

// ---- D2a/D2b: main, split by i-parity for profiler visibility + balance.
// ibase=0 -> odd i (sum 16384), ibase=1 -> even i (sum 16256); ~107us each.
__global__ __launch_bounds__(256, 8) void k_main(const unsigned* __restrict__ Jt,
                                                 const float* __restrict__ h,
                                                 const unsigned* __restrict__ seqsP,
                                                 const float* __restrict__ weights,
                                                 float* __restrict__ accL,
                                                 const int ibase) {
    __shared__ unsigned sJ[JCH * 256];   // 16 KiB: JCH blocks x 256 dwords

    const int bid = blockIdx.x;
    const int ii = ((bid >> 5) << 1) | ibase;         // 0..255 across 2 dispatches
    const int i = (L_ - 1) - ii;                      // heavy blocks first
    const int b = ((bid & 31) << 8) + threadIdx.x;    // [0, 8192)

    // packed fp16 accumulators (scaled by SCALE); elems 21..23 stay ~0 (pads)
    h2 acch[12];
    const float* hp = h + i * Q_;
#pragma unroll
    for (int m = 0; m < 10; ++m) {
        acch[m].x = (_Float16)(hp[2 * m] * SCALE);
        acch[m].y = (_Float16)(hp[2 * m + 1] * SCALE);
    }
    acch[10].x = (_Float16)(hp[20] * SCALE); acch[10].y = (_Float16)0.f;
    acch[11].x = (_Float16)0.f;              acch[11].y = (_Float16)0.f;

    const unsigned* Jrow = Jt + (size_t)(i * (i - 1) / 2) * 256;  // tri-packed
    const int nStages = i >> 4;   // full 16-j stages
    const int rem     = i & 15;

    for (int s = 0; s < nStages; ++s) {
        const int j0 = s << 4;
        {
            const uint4* src = reinterpret_cast<const uint4*>(Jrow + j0 * 256);
            uint4* dst = reinterpret_cast<uint4*>(sJ);
#pragma unroll
            for (int n = 0; n < 4; ++n) {
                dst[n * 256 + threadIdx.x] = src[n * 256 + threadIdx.x];
            }
        }
        __syncthreads();

        unsigned idxw[JCH / 4];
#pragma unroll
        for (int q = 0; q < JCH / 4; ++q) {
            idxw[q] = seqsP[((j0 >> 2) + q) * M_ + b];
        }

#pragma unroll
        for (int jj = 0; jj < JCH; ++jj) BODY(jj);

        __syncthreads();
    }

    if (rem) {
        const int j0 = nStages << 4;   // stages 16 blocks; tail may hit guard
        {
            const uint4* src = reinterpret_cast<const uint4*>(Jrow + j0 * 256);
            uint4* dst = reinterpret_cast<uint4*>(sJ);
#pragma unroll
            for (int n = 0; n < 4; ++n) {
                dst[n * 256 + threadIdx.x] = src[n * 256 + threadIdx.x];
            }
        }
        __syncthreads();

        unsigned idxw[JCH / 4];
#pragma unroll
        for (int q = 0; q < JCH / 4; ++q) {
            idxw[q] = seqsP[((j0 >> 2) + q) * M_ + b];
        }

#pragma unroll
        for (int jj = 0; jj < JCH; ++jj) {
            if (jj >= rem) break;
            BODY(jj);
        }
    }

    // unpack logits to fp32
    float l[21];
#pragma unroll
    for (int m = 0; m < 10; ++m) {
        l[2 * m]     = (float)acch[m].x * INVSCALE;
        l[2 * m + 1] = (float)acch[m].y * INVSCALE;
    }
    l[20] = (float)acch[10].x * INVSCALE;

    // label gather from packed seqs
    unsigned lw = seqsP[(i >> 2) * M_ + b];
    int lbl = (int)((lw >> ((i & 3) * 8)) & 255u);

    float m = l[0];
#pragma unroll
    for (int a = 1; a < 21; ++a) m = fmaxf(m, l[a]);
    float s = 0.f;
    float lv = l[0];
#pragma unroll
    for (int a = 0; a < 21; ++a) {
        s += __expf(l[a] - m);
        if (a > 0) lv = (a == lbl) ? l[a] : lv;
    }
    float ll = (lv - m) - __logf(s);
    float contrib = weights[b] * ll;

    float r = block_reduce_sum(contrib);
    if (threadIdx.x == 0) accL[(ibase << 12) + bid] = r;   // private slot
}

// ---- D3: finalize -- reduce all private slots + compose outputs ----
__global__ __launch_bounds__(256) void k_final(const float* __restrict__ acc2,
                                               const float* __restrict__ accL,
                                               const float* __restrict__ scal,
                                               float* __restrict__ out) {
    int t = threadIdx.x;
    float j2 = 0.f;
    for (int x = t; x < NPREPT; x += 256) j2 += acc2[x];
    j2 = block_reduce_sum(j2);
    float lls = 0.f;
    for (int x = t; x < M_; x += 256) lls += accL[x];
    lls = block_reduce_sum(lls);
    if (t == 0) {
        float wsum = fmaxf(scal[0], 1e-12f);
        float nll = -lls / wsum;
        float reg = 0.5e-6f * scal[1] + 0.5e-4f * j2;
        out[0] = nll + reg;
        out[1] = nll;
        out[2] = reg;
    }
}

extern "C" void kernel_launch(void* const* d_in, const int* in_sizes, int n_in,
                              void* d_out, int out_size, void* d_ws, size_t ws_size,
                              hipStream_t stream) {
    const int*   seqs    = (const int*)d_in[0];
    const float* weights = (const float*)d_in[1];
    const float* h       = (const float*)d_in[2];
    const float* J       = (const float*)d_in[3];
    float* out = (float*)d_out;

    char* ws = (char*)d_ws;
    float*    acc2  = (float*)ws;                         // 8160 slots
    float*    accL  = (float*)(ws + 32768);               // 8192 slots
    float*    scal  = (float*)(ws + 65536);               // wsum, h2
    unsigned* seqsP = (unsigned*)(ws + 131072);           // 2 MiB
    unsigned* Jt    = (unsigned*)(ws + 131072 + (size_t)(L_ / 4) * M_ * sizeof(unsigned));

    // no memset: every ws slot consumed is plain-stored exactly once upstream

    k_prep<<<GPREP, 256, 0, stream>>>(J, seqs, weights, h, Jt, seqsP, acc2, scal);
    k_main<<<4096, 256, 0, stream>>>(Jt, h, seqsP, weights, accL, 0);
    k_main<<<4096, 256, 0, stream>>>(Jt, h, seqsP, weights, accL, 1);
    k_final<<<1, 256, 0, stream>>>(acc2, accL, scal, out);
}